// Round 1
// baseline (2340.405 us; speedup 1.0000x reference)
//
#include <hip/hip_runtime.h>
#include <hip/hip_bf16.h>

// Problem constants (match reference)
#define SEQ   20
#define PRED  30
#define PEDS  16384
#define EMB   64
#define RNN   128
#define GATES 512
#define KTOT  192   // EMB + RNN
#define PB    64    // peds per block
#define NT    512   // threads per block (8 waves)

__device__ __forceinline__ float sigm(float x) {
    x = fminf(fmaxf(x, -30.f), 30.f);
    return 1.f / (1.f + __expf(-x));
}
__device__ __forceinline__ float tanhfast(float x) {
    x = fminf(fmaxf(x, -15.f), 15.f);
    float e = __expf(-2.f * x);
    return (1.f - e) / (1.f + e);
}

// Permute weights into [c=(wave*2+chunk)][k][32] layout, 32 contiguous f32 per
// (c,k): gates g=0..3 x j'=0..7 for j = wave*16 + chunk*8 + j'.
// Combined K axis: k<64 -> W_ih[:, k], k>=64 -> W_hh[:, k-64].
__global__ void prep_kernel(const float* __restrict__ Wih, const float* __restrict__ Whh,
                            const float* __restrict__ bih, const float* __restrict__ bhh,
                            float* __restrict__ Wp, float* __restrict__ bp) {
    int idx = blockIdx.x * blockDim.x + threadIdx.x;
    if (idx < 16 * KTOT * 32) {
        int q = idx & 31;
        int k = (idx >> 5) % KTOT;
        int c = idx / (32 * KTOT);
        int g = q >> 3, jp = q & 7;
        int row = g * RNN + (c >> 1) * 16 + (c & 1) * 8 + jp;
        float v = (k < EMB) ? Wih[row * EMB + k] : Whh[row * RNN + (k - EMB)];
        Wp[idx] = v;
    }
    if (idx < 16 * 32) {
        int q = idx & 31, c = idx >> 5;
        int g = q >> 3, jp = q & 7;
        int row = g * RNN + (c >> 1) * 16 + (c & 1) * 8 + jp;
        bp[idx] = bih[row] + bhh[row];
    }
}

__global__ __launch_bounds__(NT, 2) void lstm_kernel(
    const float* __restrict__ obs,   // [SEQ][PEDS][2]
    const float* __restrict__ Wemb,  // [EMB][2]
    const float* __restrict__ bemb,  // [EMB]
    const float* __restrict__ Wp,    // [16][KTOT][32] permuted
    const float* __restrict__ bp,    // [16][32] permuted
    const float* __restrict__ Wout,  // [2][RNN]
    const float* __restrict__ bout,  // [2]
    float* __restrict__ out)         // [PRED][PEDS][2]
{
    __shared__ float inT[KTOT][PB];  // [k][ped]: k<EMB = e, k>=EMB = h
    __shared__ float outs[PB][2];

    const int tid = threadIdx.x;
    const int p   = tid & 63;           // ped within block (lane)
    const int wj  = tid >> 6;           // wave id = j-group 0..7
    const int wu  = __builtin_amdgcn_readfirstlane(wj);
    const int pg  = blockIdx.x * PB + p;

    // h := 0
    for (int r = tid; r < RNN * PB; r += NT) (&inT[EMB][0])[r] = 0.f;

    float c[16];
#pragma unroll
    for (int q = 0; q < 16; q++) c[q] = 0.f;
    float acc[64];

    for (int step = 0; step < SEQ + PRED; ++step) {
        // ---- embedding: e = relu(x @ Wemb.T + bemb) -> inT[0..63][p]
        float x0, x1;
        if (step < SEQ) {
            x0 = obs[(size_t)(step * PEDS + pg) * 2 + 0];
            x1 = obs[(size_t)(step * PEDS + pg) * 2 + 1];
        } else {
            x0 = outs[p][0];
            x1 = outs[p][1];
        }
#pragma unroll
        for (int q = 0; q < 8; q++) {
            int ke = wj * 8 + q;
            float v = fmaf(x0, Wemb[ke * 2 + 0], fmaf(x1, Wemb[ke * 2 + 1], bemb[ke]));
            inT[ke][p] = v > 0.f ? v : 0.f;
        }
        __syncthreads();

        // ---- gates = [e,h] @ [W_ih,W_hh].T + b  (this thread: 16 j x 4 gates)
#pragma unroll
        for (int jc = 0; jc < 2; jc++) {
            const float* wpr = Wp + (size_t)((wu * 2 + jc) * KTOT) * 32;
            const float* bpr = bp + (wu * 2 + jc) * 32;
            float* a = acc + jc * 32;
#pragma unroll
            for (int q = 0; q < 32; q++) a[q] = bpr[q];
#pragma unroll 2
            for (int k = 0; k < KTOT; k++) {
                float ink = inT[k][p];
                const float* wk = wpr + k * 32;
#pragma unroll
                for (int q = 0; q < 32; q++) a[q] = fmaf(wk[q], ink, a[q]);
            }
        }
        __syncthreads();  // all inT reads done before h overwrite

        // ---- state update; write h_new into inT[EMB + j][p]
#pragma unroll
        for (int jc = 0; jc < 2; jc++) {
#pragma unroll
            for (int jj = 0; jj < 8; jj++) {
                int ai = jc * 32 + jj;
                float gi = acc[ai + 0];
                float gf = acc[ai + 8];
                float gg = acc[ai + 16];
                float go = acc[ai + 24];
                float i_ = sigm(gi), f_ = sigm(gf), g_ = tanhfast(gg), o_ = sigm(go);
                int ci = jc * 8 + jj;
                float cn = fmaf(f_, c[ci], i_ * g_);
                c[ci] = cn;
                inT[EMB + wj * 16 + ci][p] = o_ * tanhfast(cn);
            }
        }
        __syncthreads();

        // ---- output layer (needed from last encode step onward)
        if (step >= SEQ - 1) {
            if (tid < 128) {
                int oo = tid >> 6;  // p = tid & 63
                float s = bout[oo];
                for (int j = 0; j < RNN; j++)
                    s = fmaf(inT[EMB + j][p], Wout[oo * RNN + j], s);
                outs[p][oo] = s;
                if (step >= SEQ)
                    out[(size_t)((step - SEQ) * PEDS + pg) * 2 + oo] = s;
            }
            __syncthreads();
        }
    }
}

extern "C" void kernel_launch(void* const* d_in, const int* in_sizes, int n_in,
                              void* d_out, int out_size, void* d_ws, size_t ws_size,
                              hipStream_t stream) {
    const float* obs  = (const float*)d_in[0];
    const float* Wemb = (const float*)d_in[1];
    const float* bemb = (const float*)d_in[2];
    const float* Wih  = (const float*)d_in[3];
    const float* bih  = (const float*)d_in[4];
    const float* Whh  = (const float*)d_in[5];
    const float* bhh  = (const float*)d_in[6];
    const float* Wout = (const float*)d_in[7];
    const float* bout = (const float*)d_in[8];

    float* Wp = (float*)d_ws;                 // 16*192*32 f32 = 384 KB
    float* bp = Wp + 16 * KTOT * 32;          // 512 f32

    prep_kernel<<<(16 * KTOT * 32 + 255) / 256, 256, 0, stream>>>(Wih, Whh, bih, bhh, Wp, bp);
    lstm_kernel<<<PEDS / PB, NT, 0, stream>>>(obs, Wemb, bemb, Wp, bp, Wout, bout, (float*)d_out);
}

// Round 2
// 1237.633 us; speedup vs baseline: 1.8910x; 1.8910x over previous
//
#include <hip/hip_runtime.h>
#include <hip/hip_bf16.h>

#define SEQ   20
#define PRED  30
#define TSTEPS (SEQ + PRED)
#define PEDS  16384
#define EMB   64
#define RNN   128
#define KTOT  192
#define PB    64
#define NT    512

typedef __attribute__((ext_vector_type(8))) short short8;
typedef __attribute__((ext_vector_type(4))) float f32x4;

__device__ __forceinline__ unsigned short f2bf(float f) {
    unsigned u = __float_as_uint(f);
    u += 0x7FFFu + ((u >> 16) & 1u);
    return (unsigned short)(u >> 16);
}
__device__ __forceinline__ float bf2f(unsigned short s) {
    return __uint_as_float(((unsigned)s) << 16);
}
__device__ __forceinline__ float sigm(float x) {
    x = fminf(fmaxf(x, -30.f), 30.f);
    return 1.f / (1.f + __expf(-x));
}
__device__ __forceinline__ float tanhfast(float x) {
    x = fminf(fmaxf(x, -15.f), 15.f);
    float e = __expf(-2.f * x);
    return (1.f - e) / (1.f + e);
}

// B fragments pre-permuted: idx = ((nt*6 + kt)*64 + lane)*8 + i
// n = nt*16 + (lane&15); k = kt*32 + (lane>>4)*8 + i
// W_cat[n][k]: k<64 -> W_ih[n][k], else W_hh[n][k-64]. Split bf16 hi/lo.
__global__ void prep_kernel(const float* __restrict__ Wih, const float* __restrict__ Whh,
                            unsigned short* __restrict__ BpHi, unsigned short* __restrict__ BpLo) {
    int idx = blockIdx.x * blockDim.x + threadIdx.x;
    if (idx >= 32 * 6 * 64 * 8) return;
    int i  = idx & 7;
    int l  = (idx >> 3) & 63;
    int v  = idx >> 9;
    int kt = v % 6, nt = v / 6;
    int n = nt * 16 + (l & 15);
    int k = kt * 32 + ((l >> 4) << 3) + i;
    float val = (k < EMB) ? Wih[n * EMB + k] : Whh[n * RNN + (k - EMB)];
    unsigned short hb = f2bf(val);
    BpHi[idx] = hb;
    BpLo[idx] = f2bf(val - bf2f(hb));
}

__global__ __launch_bounds__(NT, 2) void lstm_kernel(
    const float* __restrict__ obs,
    const float* __restrict__ Wemb, const float* __restrict__ bemb,
    const float* __restrict__ bih,  const float* __restrict__ bhh,
    const unsigned short* __restrict__ BpHi, const unsigned short* __restrict__ BpLo,
    const float* __restrict__ Wout, const float* __restrict__ bout,
    float* __restrict__ out)
{
    // A = [e(64) ; h(128)] as bf16 hi/lo, row-major [64 ped][192 k], XOR-swizzled.
    __shared__ __align__(16) char smAhi[64 * KTOT * 2];
    __shared__ __align__(16) char smAlo[64 * KTOT * 2];
    __shared__ __align__(16) char smH32[64 * RNN * 4];   // f32 h for output layer
    __shared__ float part[64 * 2 * 4];
    __shared__ float outs[64 * 2];

    const int tid = threadIdx.x;
    const int l   = tid & 63;
    const int w   = __builtin_amdgcn_readfirstlane(tid >> 6);  // wave 0..7
    const int pg  = blockIdx.x * PB + l;

    for (int r = tid; r < (64 * KTOT * 2) / 4; r += NT) ((int*)smAhi)[r] = 0;
    for (int r = tid; r < (64 * KTOT * 2) / 4; r += NT) ((int*)smAlo)[r] = 0;
    for (int r = tid; r < 64 * RNN; r += NT) ((int*)smH32)[r] = 0;

    // hoisted embedding weights: ke = w*8 + q
    float we0[8], we1[8], be[8];
#pragma unroll
    for (int q = 0; q < 8; ++q) {
        int ke = w * 8 + q;
        we0[q] = Wemb[ke * 2 + 0];
        we1[q] = Wemb[ke * 2 + 1];
        be[q]  = bemb[ke];
    }
    // gate bias: n = g*128 + w*16 + (l&15)
    float bias[4];
#pragma unroll
    for (int g = 0; g < 4; ++g) {
        int n = g * RNN + w * 16 + (l & 15);
        bias[g] = bih[n] + bhh[n];
    }

    float c[16];
#pragma unroll
    for (int q = 0; q < 16; ++q) c[q] = 0.f;

    const short8* BH = (const short8*)BpHi;
    const short8* BL = (const short8*)BpLo;

    const int jlane = w * 16 + (l & 15);   // this lane's j column
    const int lrow  = (l >> 4) << 2;       // C/D row base
    const int kgrp  = (l >> 4) << 3;       // A/B k-group base

    __syncthreads();

    for (int step = 0; step < TSTEPS; ++step) {
        // ---- E: embedding e = relu(x @ Wemb.T + bemb), thread: ped=l, ke=w*8..+8
        float x0, x1;
        if (step < SEQ) {
            const float* xp = obs + ((size_t)step * PEDS + pg) * 2;
            x0 = xp[0]; x1 = xp[1];
        } else {
            x0 = outs[l * 2 + 0];
            x1 = outs[l * 2 + 1];
        }
        {
            short8 vh, vl;
#pragma unroll
            for (int q = 0; q < 8; ++q) {
                float v = fmaf(x0, we0[q], fmaf(x1, we1[q], be[q]));
                v = v > 0.f ? v : 0.f;
                unsigned short hb = f2bf(v);
                vh[q] = (short)hb;
                vl[q] = (short)f2bf(v - bf2f(hb));
            }
            int off = (l * 384 + w * 16) ^ ((l & 7) << 4);
            *(short8*)(smAhi + off) = vh;
            *(short8*)(smAlo + off) = vl;
        }
        __syncthreads();  // B1: e + prev h visible

        // ---- G: gates[64x512] = A[64x192] @ B[192x512] + bias (bf16x3 MFMA)
        f32x4 acc[4][4];  // [mt][gate]
#pragma unroll
        for (int mt = 0; mt < 4; ++mt)
#pragma unroll
            for (int g = 0; g < 4; ++g) {
                acc[mt][g][0] = bias[g]; acc[mt][g][1] = bias[g];
                acc[mt][g][2] = bias[g]; acc[mt][g][3] = bias[g];
            }
#pragma unroll
        for (int kt = 0; kt < 6; ++kt) {
            short8 ah[4], al[4];
#pragma unroll
            for (int mt = 0; mt < 4; ++mt) {
                int ped = mt * 16 + (l & 15);
                int off = (ped * 384 + (kt * 32 + kgrp) * 2) ^ ((ped & 7) << 4);
                ah[mt] = *(const short8*)(smAhi + off);
                al[mt] = *(const short8*)(smAlo + off);
            }
#pragma unroll
            for (int g = 0; g < 4; ++g) {
                int bi = ((g * 8 + w) * 6 + kt) * 64 + l;
                short8 bh = BH[bi];
                short8 bl = BL[bi];
#pragma unroll
                for (int mt = 0; mt < 4; ++mt) {
                    acc[mt][g] = __builtin_amdgcn_mfma_f32_16x16x32_bf16(ah[mt], bh, acc[mt][g], 0, 0, 0);
                    acc[mt][g] = __builtin_amdgcn_mfma_f32_16x16x32_bf16(al[mt], bh, acc[mt][g], 0, 0, 0);
                    acc[mt][g] = __builtin_amdgcn_mfma_f32_16x16x32_bf16(ah[mt], bl, acc[mt][g], 0, 0, 0);
                }
            }
        }
        __syncthreads();  // B2: all A reads done before h overwrite

        // ---- S: nonlinearities + c/h update; lane owns (ped = mt*16+lrow+r, j = jlane)
#pragma unroll
        for (int mt = 0; mt < 4; ++mt) {
#pragma unroll
            for (int r = 0; r < 4; ++r) {
                float gi = acc[mt][0][r], gf = acc[mt][1][r];
                float gg = acc[mt][2][r], go = acc[mt][3][r];
                float i_ = sigm(gi), f_ = sigm(gf), g_ = tanhfast(gg), o_ = sigm(go);
                float cn = fmaf(f_, c[mt * 4 + r], i_ * g_);
                c[mt * 4 + r] = cn;
                float hn = o_ * tanhfast(cn);
                int ped = mt * 16 + lrow + r;
                unsigned short hb = f2bf(hn);
                unsigned short lb = f2bf(hn - bf2f(hb));
                int offb = (ped * 384 + (EMB + jlane) * 2) ^ ((ped & 7) << 4);
                *(short*)(smAhi + offb) = (short)hb;
                *(short*)(smAlo + offb) = (short)lb;
                *(float*)(smH32 + ((ped * 512 + jlane * 4) ^ ((ped & 7) << 4))) = hn;
            }
        }

        // ---- O: out = h @ Wout.T + bout (wave w: oo=w&1, j-quarter=w>>1)
        if (step >= SEQ - 1) {
            __syncthreads();  // B3: h32 visible
            int oo = w & 1, jq = w >> 1;
            float s = 0.f;
#pragma unroll
            for (int t = 0; t < 8; ++t) {
                int j = jq * 32 + t * 4;
                f32x4 hv = *(const f32x4*)(smH32 + ((l * 512 + j * 4) ^ ((l & 7) << 4)));
                const float* wr = Wout + oo * RNN + j;
                s = fmaf(hv[0], wr[0], s);
                s = fmaf(hv[1], wr[1], s);
                s = fmaf(hv[2], wr[2], s);
                s = fmaf(hv[3], wr[3], s);
            }
            part[(l * 2 + oo) * 4 + jq] = s;
            __syncthreads();  // B4
            if (tid < 128) {
                int pp = tid & 63, o2 = tid >> 6;
                const float* pr = &part[(pp * 2 + o2) * 4];
                float o = bout[o2] + ((pr[0] + pr[1]) + (pr[2] + pr[3]));
                outs[pp * 2 + o2] = o;
                if (step >= SEQ)
                    out[((size_t)(step - SEQ) * PEDS + (blockIdx.x * PB + pp)) * 2 + o2] = o;
            }
            __syncthreads();  // B5: outs visible for next E
        }
    }
}

extern "C" void kernel_launch(void* const* d_in, const int* in_sizes, int n_in,
                              void* d_out, int out_size, void* d_ws, size_t ws_size,
                              hipStream_t stream) {
    const float* obs  = (const float*)d_in[0];
    const float* Wemb = (const float*)d_in[1];
    const float* bemb = (const float*)d_in[2];
    const float* Wih  = (const float*)d_in[3];
    const float* bih  = (const float*)d_in[4];
    const float* Whh  = (const float*)d_in[5];
    const float* bhh  = (const float*)d_in[6];
    const float* Wout = (const float*)d_in[7];
    const float* bout = (const float*)d_in[8];

    unsigned short* BpHi = (unsigned short*)d_ws;       // 98304 u16 = 192 KB
    unsigned short* BpLo = BpHi + 32 * 6 * 64 * 8;      // 192 KB

    prep_kernel<<<(32 * 6 * 64 * 8 + 255) / 256, 256, 0, stream>>>(Wih, Whh, BpHi, BpLo);
    lstm_kernel<<<PEDS / PB, NT, 0, stream>>>(obs, Wemb, bemb, bih, bhh,
                                              BpHi, BpLo, Wout, bout, (float*)d_out);
}

// Round 3
// 1182.904 us; speedup vs baseline: 1.9785x; 1.0463x over previous
//
#include <hip/hip_runtime.h>
#include <hip/hip_bf16.h>

#define SEQ   20
#define PRED  30
#define TSTEPS (SEQ + PRED)
#define PEDS  16384
#define EMB   64
#define RNN   128
#define KTOT  192
#define PB    64
#define NT    512

typedef __attribute__((ext_vector_type(8))) short short8;
typedef __attribute__((ext_vector_type(4))) float f32x4;

__device__ __forceinline__ unsigned short f2bf(float f) {
    unsigned u = __float_as_uint(f);
    u += 0x7FFFu + ((u >> 16) & 1u);
    return (unsigned short)(u >> 16);
}
__device__ __forceinline__ float bf2f(unsigned short s) {
    return __uint_as_float(((unsigned)s) << 16);
}
__device__ __forceinline__ float sigm(float x) {
    x = fminf(fmaxf(x, -30.f), 30.f);
    return 1.f / (1.f + __expf(-x));
}
__device__ __forceinline__ float tanhfast(float x) {
    x = fminf(fmaxf(x, -15.f), 15.f);
    float e = __expf(-2.f * x);
    return (1.f - e) / (1.f + e);
}

// B fragments pre-permuted: idx = ((nt*6 + kt)*64 + lane)*8 + i
// n = nt*16 + (lane&15); k = kt*32 + (lane>>4)*8 + i
// W_cat[n][k]: k<64 -> W_ih[n][k], else W_hh[n][k-64]. Split bf16 hi/lo.
// Also: packed embedding weights ewp[ke][4] = {Wemb[ke][0], Wemb[ke][1], bemb[ke], 0}
__global__ void prep_kernel(const float* __restrict__ Wih, const float* __restrict__ Whh,
                            const float* __restrict__ Wemb, const float* __restrict__ bemb,
                            unsigned short* __restrict__ BpHi, unsigned short* __restrict__ BpLo,
                            float* __restrict__ ewp) {
    int idx = blockIdx.x * blockDim.x + threadIdx.x;
    if (idx < 64) {
        ewp[idx * 4 + 0] = Wemb[idx * 2 + 0];
        ewp[idx * 4 + 1] = Wemb[idx * 2 + 1];
        ewp[idx * 4 + 2] = bemb[idx];
        ewp[idx * 4 + 3] = 0.f;
    }
    if (idx >= 32 * 6 * 64 * 8) return;
    int i  = idx & 7;
    int l  = (idx >> 3) & 63;
    int v  = idx >> 9;
    int kt = v % 6, nt = v / 6;
    int n = nt * 16 + (l & 15);
    int k = kt * 32 + ((l >> 4) << 3) + i;
    float val = (k < EMB) ? Wih[n * EMB + k] : Whh[n * RNN + (k - EMB)];
    unsigned short hb = f2bf(val);
    BpHi[idx] = hb;
    BpLo[idx] = f2bf(val - bf2f(hb));
}

__global__ __launch_bounds__(NT, 2) void lstm_kernel(
    const float* __restrict__ obs,
    const float* __restrict__ ewp,
    const float* __restrict__ bih,  const float* __restrict__ bhh,
    const unsigned short* __restrict__ BpHi, const unsigned short* __restrict__ BpLo,
    const float* __restrict__ Wout, const float* __restrict__ bout,
    float* __restrict__ out)
{
    // A = [e(64) ; h(128)] bf16 hi/lo planes, row-major [64 ped][192 k], XOR-swizzled,
    // double-buffered across steps.
    __shared__ __align__(16) char smA[2][2][64 * KTOT * 2];  // [buf][hi/lo]
    __shared__ float part[64 * 2 * 4];
    __shared__ float outs[64 * 2];

    const int tid = threadIdx.x;
    const int l   = tid & 63;
    const int w   = __builtin_amdgcn_readfirstlane(tid >> 6);  // wave 0..7
    const int pg  = blockIdx.x * PB + l;

    // zero buf0 (h region must be 0 at step 0; zeroing all of it is harmless)
    for (int r = tid; r < (64 * KTOT * 2) / 4; r += NT) {
        ((int*)smA[0][0])[r] = 0;
        ((int*)smA[0][1])[r] = 0;
    }

    // gate bias: n = g*128 + w*16 + (l&15)
    float bias[4];
#pragma unroll
    for (int g = 0; g < 4; ++g) {
        int n = g * RNN + w * 16 + (l & 15);
        bias[g] = bih[n] + bhh[n];
    }

    const short8* BH = (const short8*)BpHi;
    const short8* BL = (const short8*)BpLo;

    // persist Bh in registers: 24 frags = 96 VGPR
    short8 Bh[4][6];
#pragma unroll
    for (int g = 0; g < 4; ++g)
#pragma unroll
        for (int kt = 0; kt < 6; ++kt)
            Bh[g][kt] = BH[((g * 8 + w) * 6 + kt) * 64 + l];

    // Bl rotation buffer; preload kt=0
    short8 bl[2][4];
#pragma unroll
    for (int g = 0; g < 4; ++g)
        bl[0][g] = BL[((g * 8 + w) * 6 + 0) * 64 + l];

    float c[16];
#pragma unroll
    for (int q = 0; q < 16; ++q) c[q] = 0.f;

    const int jlane = w * 16 + (l & 15);   // this lane's j column
    const int lrow  = (l >> 4) << 2;       // C/D row base
    const int kgrp  = (l >> 4) << 3;       // A/B k-group base

    int cur = 0;
    __syncthreads();  // zero-init visible before E writes overlap regions

    for (int step = 0; step < TSTEPS; ++step) {
        const int nxt = cur ^ 1;

        // ---- E: e = relu(x @ Wemb.T + bemb) -> smA[cur] k=0..63
        float x0, x1;
        if (step < SEQ) {
            const float* xp = obs + ((size_t)step * PEDS + pg) * 2;
            x0 = xp[0]; x1 = xp[1];
        } else {
            x0 = outs[l * 2 + 0];
            x1 = outs[l * 2 + 1];
        }
        {
            short8 vh, vl;
#pragma unroll
            for (int q = 0; q < 8; ++q) {
                const f32x4 ew = *(const f32x4*)(ewp + (w * 8 + q) * 4);
                float v = fmaf(x0, ew[0], fmaf(x1, ew[1], ew[2]));
                v = v > 0.f ? v : 0.f;
                unsigned short hb = f2bf(v);
                vh[q] = (short)hb;
                vl[q] = (short)f2bf(v - bf2f(hb));
            }
            int off = (l * 384 + w * 16) ^ ((l & 7) << 4);
            *(short8*)(smA[cur][0] + off) = vh;
            *(short8*)(smA[cur][1] + off) = vl;
        }
        __syncthreads();  // e (this step) + h (prev step) in smA[cur] visible

        // ---- G: gates[64x512] = A[64x192] @ B[192x512] + bias (bf16x3 MFMA)
        f32x4 acc[4][4];  // [mt][gate]
#pragma unroll
        for (int mt = 0; mt < 4; ++mt)
#pragma unroll
            for (int g = 0; g < 4; ++g) {
                acc[mt][g][0] = bias[g]; acc[mt][g][1] = bias[g];
                acc[mt][g][2] = bias[g]; acc[mt][g][3] = bias[g];
            }
#pragma unroll
        for (int kt = 0; kt < 6; ++kt) {
            const int pcur = kt & 1, pnxt = pcur ^ 1;
            // cyclic prefetch: next kt's Bl (kt=5 prefetches kt=0 for next step)
            const int ktn = (kt < 5) ? kt + 1 : 0;
#pragma unroll
            for (int g = 0; g < 4; ++g)
                bl[pnxt][g] = BL[((g * 8 + w) * 6 + ktn) * 64 + l];
#pragma unroll
            for (int mt = 0; mt < 4; ++mt) {
                int ped = mt * 16 + (l & 15);
                int off = (ped * 384 + (kt * 32 + kgrp) * 2) ^ ((ped & 7) << 4);
                short8 ah = *(const short8*)(smA[cur][0] + off);
                short8 al = *(const short8*)(smA[cur][1] + off);
#pragma unroll
                for (int g = 0; g < 4; ++g) {
                    acc[mt][g] = __builtin_amdgcn_mfma_f32_16x16x32_bf16(ah, Bh[g][kt], acc[mt][g], 0, 0, 0);
                    acc[mt][g] = __builtin_amdgcn_mfma_f32_16x16x32_bf16(al, Bh[g][kt], acc[mt][g], 0, 0, 0);
                    acc[mt][g] = __builtin_amdgcn_mfma_f32_16x16x32_bf16(ah, bl[pcur][g], acc[mt][g], 0, 0, 0);
                }
            }
        }

        // ---- S: nonlinearities + c/h update; h_new -> smA[nxt] (no barrier needed:
        // smA[nxt] was last READ in G two steps ago, ordered by the barrier above)
#pragma unroll
        for (int mt = 0; mt < 4; ++mt) {
#pragma unroll
            for (int r = 0; r < 4; ++r) {
                float gi = acc[mt][0][r], gf = acc[mt][1][r];
                float gg = acc[mt][2][r], go = acc[mt][3][r];
                float i_ = sigm(gi), f_ = sigm(gf), g_ = tanhfast(gg), o_ = sigm(go);
                float cn = fmaf(f_, c[mt * 4 + r], i_ * g_);
                c[mt * 4 + r] = cn;
                float hn = o_ * tanhfast(cn);
                int ped = mt * 16 + lrow + r;
                unsigned short hb = f2bf(hn);
                unsigned short lb = f2bf(hn - bf2f(hb));
                int offb = (ped * 384 + (EMB + jlane) * 2) ^ ((ped & 7) << 4);
                *(short*)(smA[nxt][0] + offb) = (short)hb;
                *(short*)(smA[nxt][1] + offb) = (short)lb;
            }
        }

        // ---- O: out = h @ Wout.T + bout, h reconstructed as hi+lo from smA[nxt]
        if (step >= SEQ - 1) {
            __syncthreads();  // B3: h(step) in smA[nxt] visible
            const int oo = w & 1, jq = w >> 1;
            float s = 0.f;
#pragma unroll
            for (int t = 0; t < 4; ++t) {
                int j = jq * 32 + t * 8;
                int off = (l * 384 + (EMB + j) * 2) ^ ((l & 7) << 4);
                short8 hh = *(const short8*)(smA[nxt][0] + off);
                short8 hl = *(const short8*)(smA[nxt][1] + off);
                const f32x4 w0 = *(const f32x4*)(Wout + oo * RNN + j);
                const f32x4 w1 = *(const f32x4*)(Wout + oo * RNN + j + 4);
#pragma unroll
                for (int i = 0; i < 4; ++i) {
                    s = fmaf(bf2f((unsigned short)hh[i]) + bf2f((unsigned short)hl[i]), w0[i], s);
                    s = fmaf(bf2f((unsigned short)hh[i + 4]) + bf2f((unsigned short)hl[i + 4]), w1[i], s);
                }
            }
            part[(l * 2 + oo) * 4 + jq] = s;
            __syncthreads();  // B4
            if (tid < 128) {
                int pp = tid & 63, o2 = tid >> 6;
                const float* pr = &part[(pp * 2 + o2) * 4];
                float o = bout[o2] + ((pr[0] + pr[1]) + (pr[2] + pr[3]));
                outs[pp * 2 + o2] = o;
                if (step >= SEQ)
                    out[((size_t)(step - SEQ) * PEDS + (blockIdx.x * PB + pp)) * 2 + o2] = o;
            }
            __syncthreads();  // B5: outs visible for next E
        }
        cur = nxt;
    }
}

extern "C" void kernel_launch(void* const* d_in, const int* in_sizes, int n_in,
                              void* d_out, int out_size, void* d_ws, size_t ws_size,
                              hipStream_t stream) {
    const float* obs  = (const float*)d_in[0];
    const float* Wemb = (const float*)d_in[1];
    const float* bemb = (const float*)d_in[2];
    const float* Wih  = (const float*)d_in[3];
    const float* bih  = (const float*)d_in[4];
    const float* Whh  = (const float*)d_in[5];
    const float* bhh  = (const float*)d_in[6];
    const float* Wout = (const float*)d_in[7];
    const float* bout = (const float*)d_in[8];

    unsigned short* BpHi = (unsigned short*)d_ws;       // 98304 u16 = 192 KB
    unsigned short* BpLo = BpHi + 32 * 6 * 64 * 8;      // 192 KB
    float*          ewp  = (float*)(BpLo + 32 * 6 * 64 * 8);  // 64*4 f32 = 1 KB

    prep_kernel<<<(32 * 6 * 64 * 8 + 255) / 256, 256, 0, stream>>>(Wih, Whh, Wemb, bemb, BpHi, BpLo, ewp);
    lstm_kernel<<<PEDS / PB, NT, 0, stream>>>(obs, ewp, bih, bhh,
                                              BpHi, BpLo, Wout, bout, (float*)d_out);
}

// Round 4
// 1148.412 us; speedup vs baseline: 2.0379x; 1.0300x over previous
//
#include <hip/hip_runtime.h>
#include <hip/hip_bf16.h>

#define SEQ   20
#define PRED  30
#define TSTEPS (SEQ + PRED)
#define PEDS  16384
#define EMB   64
#define RNN   128
#define KTOT  192
#define PB    64
#define NT    512

typedef __attribute__((ext_vector_type(8))) short short8;
typedef __attribute__((ext_vector_type(4))) float f32x4;

__device__ __forceinline__ unsigned short f2bf(float f) {
    unsigned u = __float_as_uint(f);
    u += 0x7FFFu + ((u >> 16) & 1u);
    return (unsigned short)(u >> 16);
}
__device__ __forceinline__ float bf2f(unsigned short s) {
    return __uint_as_float(((unsigned)s) << 16);
}
// gates bounded (|g| < ~40) -> exp(-x) never overflows f32; no clamp needed
__device__ __forceinline__ float sigm(float x) {
    return 1.f / (1.f + __expf(-x));
}
// one-sided clamp: only x << 0 can overflow exp(-2x)
__device__ __forceinline__ float tanhfast(float x) {
    x = fmaxf(x, -15.f);
    float e = __expf(-2.f * x);
    return (1.f - e) / (1.f + e);
}

// B fragments pre-permuted: idx = ((nt*6 + kt)*64 + lane)*8 + i
// n = nt*16 + (lane&15); k = kt*32 + (lane>>4)*8 + i
// W_cat[n][k]: k<64 -> W_ih[n][k], else W_hh[n][k-64]. Split bf16 hi/lo.
// Also: packed embedding weights ewp[ke][4] = {Wemb[ke][0], Wemb[ke][1], bemb[ke], 0}
__global__ void prep_kernel(const float* __restrict__ Wih, const float* __restrict__ Whh,
                            const float* __restrict__ Wemb, const float* __restrict__ bemb,
                            unsigned short* __restrict__ BpHi, unsigned short* __restrict__ BpLo,
                            float* __restrict__ ewp) {
    int idx = blockIdx.x * blockDim.x + threadIdx.x;
    if (idx < 64) {
        ewp[idx * 4 + 0] = Wemb[idx * 2 + 0];
        ewp[idx * 4 + 1] = Wemb[idx * 2 + 1];
        ewp[idx * 4 + 2] = bemb[idx];
        ewp[idx * 4 + 3] = 0.f;
    }
    if (idx >= 32 * 6 * 64 * 8) return;
    int i  = idx & 7;
    int l  = (idx >> 3) & 63;
    int v  = idx >> 9;
    int kt = v % 6, nt = v / 6;
    int n = nt * 16 + (l & 15);
    int k = kt * 32 + ((l >> 4) << 3) + i;
    float val = (k < EMB) ? Wih[n * EMB + k] : Whh[n * RNN + (k - EMB)];
    unsigned short hb = f2bf(val);
    BpHi[idx] = hb;
    BpLo[idx] = f2bf(val - bf2f(hb));
}

__global__ __launch_bounds__(NT, 2) void lstm_kernel(
    const float* __restrict__ obs,
    const float* __restrict__ ewp,
    const float* __restrict__ bih,  const float* __restrict__ bhh,
    const unsigned short* __restrict__ BpHi, const unsigned short* __restrict__ BpLo,
    const float* __restrict__ Wout, const float* __restrict__ bout,
    float* __restrict__ out)
{
    // A = [e(64) ; h(128)] bf16 hi/lo planes, row-major [64 ped][192 k], XOR-swizzled,
    // double-buffered across steps.
    __shared__ __align__(16) char smA[2][2][64 * KTOT * 2];  // [buf][hi/lo]
    __shared__ float part[64 * 2 * 4];
    __shared__ float outs[64 * 2];

    const int tid = threadIdx.x;
    const int l   = tid & 63;
    const int w   = __builtin_amdgcn_readfirstlane(tid >> 6);  // wave 0..7
    const int pg  = blockIdx.x * PB + l;

    // zero buf0 (h region must be 0 at step 0)
    for (int r = tid; r < (64 * KTOT * 2) / 4; r += NT) {
        ((int*)smA[0][0])[r] = 0;
        ((int*)smA[0][1])[r] = 0;
    }

    // gate bias: n = g*128 + w*16 + (l&15)
    float bias[4];
#pragma unroll
    for (int g = 0; g < 4; ++g) {
        int n = g * RNN + w * 16 + (l & 15);
        bias[g] = bih[n] + bhh[n];
    }

    const short8* BH = (const short8*)BpHi;
    const short8* BL = (const short8*)BpLo;

    // persist Bh in registers: 24 frags = 96 VGPR; the empty asm makes the
    // values opaque so the compiler cannot rematerialize the loads in-loop.
    short8 Bh[4][6];
#pragma unroll
    for (int g = 0; g < 4; ++g)
#pragma unroll
        for (int kt = 0; kt < 6; ++kt)
            Bh[g][kt] = BH[((g * 8 + w) * 6 + kt) * 64 + l];
#pragma unroll
    for (int g = 0; g < 4; ++g)
#pragma unroll
        for (int kt = 0; kt < 6; ++kt)
            asm volatile("" : "+v"(Bh[g][kt]));

    // Bl rotation buffer; preload kt=0
    short8 bl[2][4];
#pragma unroll
    for (int g = 0; g < 4; ++g)
        bl[0][g] = BL[((g * 8 + w) * 6 + 0) * 64 + l];

    float c[16];
#pragma unroll
    for (int q = 0; q < 16; ++q) c[q] = 0.f;

    const int jlane = w * 16 + (l & 15);   // this lane's j column
    const int lrow  = (l >> 4) << 2;       // C/D row base
    const int kgrp  = (l >> 4) << 3;       // A/B k-group base

    int cur = 0;
    __syncthreads();  // zero-init visible

    for (int step = 0; step < TSTEPS; ++step) {
        const int nxt = cur ^ 1;

        // ---- E: e = relu(x @ Wemb.T + bemb) -> smA[cur] k=0..63
        float x0, x1;
        if (step < SEQ) {
            const float* xp = obs + ((size_t)step * PEDS + pg) * 2;
            x0 = xp[0]; x1 = xp[1];
        } else {
            x0 = outs[l * 2 + 0];
            x1 = outs[l * 2 + 1];
        }
        {
            short8 vh, vl;
#pragma unroll
            for (int q = 0; q < 8; ++q) {
                const f32x4 ew = *(const f32x4*)(ewp + (w * 8 + q) * 4);
                float v = fmaf(x0, ew[0], fmaf(x1, ew[1], ew[2]));
                v = v > 0.f ? v : 0.f;
                unsigned short hb = f2bf(v);
                vh[q] = (short)hb;
                vl[q] = (short)f2bf(v - bf2f(hb));
            }
            int off = (l * 384 + w * 16) ^ ((l & 7) << 4);
            *(short8*)(smA[cur][0] + off) = vh;
            *(short8*)(smA[cur][1] + off) = vl;
        }
        __syncthreads();  // B1: e (this step) + h (prev step) in smA[cur] visible

        // ---- G: gates[64x512] = A[64x192] @ B[192x512] + bias (bf16x3 MFMA)
        f32x4 acc[4][4];  // [mt][gate]
#pragma unroll
        for (int mt = 0; mt < 4; ++mt)
#pragma unroll
            for (int g = 0; g < 4; ++g) {
                acc[mt][g][0] = bias[g]; acc[mt][g][1] = bias[g];
                acc[mt][g][2] = bias[g]; acc[mt][g][3] = bias[g];
            }
#pragma unroll
        for (int kt = 0; kt < 6; ++kt) {
            const int pcur = kt & 1, pnxt = pcur ^ 1;
            // cyclic prefetch: next kt's Bl (kt=5 prefetches kt=0 for next step)
            const int ktn = (kt < 5) ? kt + 1 : 0;
#pragma unroll
            for (int g = 0; g < 4; ++g)
                bl[pnxt][g] = BL[((g * 8 + w) * 6 + ktn) * 64 + l];
#pragma unroll
            for (int mt = 0; mt < 4; ++mt) {
                int ped = mt * 16 + (l & 15);
                int off = (ped * 384 + (kt * 32 + kgrp) * 2) ^ ((ped & 7) << 4);
                short8 ah = *(const short8*)(smA[cur][0] + off);
                short8 al = *(const short8*)(smA[cur][1] + off);
#pragma unroll
                for (int g = 0; g < 4; ++g) {
                    acc[mt][g] = __builtin_amdgcn_mfma_f32_16x16x32_bf16(ah, Bh[g][kt], acc[mt][g], 0, 0, 0);
                    acc[mt][g] = __builtin_amdgcn_mfma_f32_16x16x32_bf16(al, Bh[g][kt], acc[mt][g], 0, 0, 0);
                    acc[mt][g] = __builtin_amdgcn_mfma_f32_16x16x32_bf16(ah, bl[pcur][g], acc[mt][g], 0, 0, 0);
                }
            }
        }

        // ---- S: nonlinearities + c/h update; h_new -> smA[nxt] (ordered by B1)
#pragma unroll
        for (int mt = 0; mt < 4; ++mt) {
#pragma unroll
            for (int r = 0; r < 4; ++r) {
                float gi = acc[mt][0][r], gf = acc[mt][1][r];
                float gg = acc[mt][2][r], go = acc[mt][3][r];
                float i_ = sigm(gi), f_ = sigm(gf), g_ = tanhfast(gg), o_ = sigm(go);
                float cn = fmaf(f_, c[mt * 4 + r], i_ * g_);
                c[mt * 4 + r] = cn;
                float hn = o_ * tanhfast(cn);
                int ped = mt * 16 + lrow + r;
                unsigned short hb = f2bf(hn);
                unsigned short lb = f2bf(hn - bf2f(hb));
                int offb = (ped * 384 + (EMB + jlane) * 2) ^ ((ped & 7) << 4);
                *(short*)(smA[nxt][0] + offb) = (short)hb;
                *(short*)(smA[nxt][1] + offb) = (short)lb;
            }
        }

        // ---- O: out = h @ Wout.T + bout, h reconstructed as hi+lo from smA[nxt]
        if (step >= SEQ - 1) {
            __syncthreads();  // B3: h(step) in smA[nxt] visible
            const int oo = w & 1, jq = w >> 1;
            float s = 0.f;
#pragma unroll
            for (int t = 0; t < 4; ++t) {
                int j = jq * 32 + t * 8;
                int off = (l * 384 + (EMB + j) * 2) ^ ((l & 7) << 4);
                short8 hh = *(const short8*)(smA[nxt][0] + off);
                short8 hl = *(const short8*)(smA[nxt][1] + off);
                const f32x4 w0 = *(const f32x4*)(Wout + oo * RNN + j);
                const f32x4 w1 = *(const f32x4*)(Wout + oo * RNN + j + 4);
#pragma unroll
                for (int i = 0; i < 4; ++i) {
                    s = fmaf(bf2f((unsigned short)hh[i]) + bf2f((unsigned short)hl[i]), w0[i], s);
                    s = fmaf(bf2f((unsigned short)hh[i + 4]) + bf2f((unsigned short)hl[i + 4]), w1[i], s);
                }
            }
            part[(l * 2 + oo) * 4 + jq] = s;
            __syncthreads();  // B4
            if (tid < 128) {
                int pp = tid & 63, o2 = tid >> 6;
                const float* pr = &part[(pp * 2 + o2) * 4];
                float o = bout[o2] + ((pr[0] + pr[1]) + (pr[2] + pr[3]));
                outs[pp * 2 + o2] = o;
                if (step >= SEQ)
                    out[((size_t)(step - SEQ) * PEDS + (blockIdx.x * PB + pp)) * 2 + o2] = o;
            }
            __syncthreads();  // B5: outs visible for next E
        }
        cur = nxt;
    }
}

extern "C" void kernel_launch(void* const* d_in, const int* in_sizes, int n_in,
                              void* d_out, int out_size, void* d_ws, size_t ws_size,
                              hipStream_t stream) {
    const float* obs  = (const float*)d_in[0];
    const float* Wemb = (const float*)d_in[1];
    const float* bemb = (const float*)d_in[2];
    const float* Wih  = (const float*)d_in[3];
    const float* bih  = (const float*)d_in[4];
    const float* Whh  = (const float*)d_in[5];
    const float* bhh  = (const float*)d_in[6];
    const float* Wout = (const float*)d_in[7];
    const float* bout = (const float*)d_in[8];

    unsigned short* BpHi = (unsigned short*)d_ws;       // 98304 u16 = 192 KB
    unsigned short* BpLo = BpHi + 32 * 6 * 64 * 8;      // 192 KB
    float*          ewp  = (float*)(BpLo + 32 * 6 * 64 * 8);  // 64*4 f32 = 1 KB

    prep_kernel<<<(32 * 6 * 64 * 8 + 255) / 256, 256, 0, stream>>>(Wih, Whh, Wemb, bemb, BpHi, BpLo, ewp);
    lstm_kernel<<<PEDS / PB, NT, 0, stream>>>(obs, ewp, bih, bhh,
                                              BpHi, BpLo, Wout, bout, (float*)d_out);
}

// Round 5
// 1146.806 us; speedup vs baseline: 2.0408x; 1.0014x over previous
//
#include <hip/hip_runtime.h>
#include <hip/hip_bf16.h>

#define SEQ   20
#define PRED  30
#define TSTEPS (SEQ + PRED)
#define PEDS  16384
#define EMB   64
#define RNN   128
#define KTOT  192
#define PB    64
#define NT    512

typedef __attribute__((ext_vector_type(8))) short short8;
typedef __attribute__((ext_vector_type(4))) float f32x4;

__device__ __forceinline__ unsigned short f2bf(float f) {
    unsigned u = __float_as_uint(f);
    u += 0x7FFFu + ((u >> 16) & 1u);
    return (unsigned short)(u >> 16);
}
__device__ __forceinline__ float bf2f(unsigned short s) {
    return __uint_as_float(((unsigned)s) << 16);
}
// gates bounded -> exp(-x) never overflows f32 for realistic values
__device__ __forceinline__ float sigm(float x) {
    return 1.f / (1.f + __expf(-x));
}
__device__ __forceinline__ float tanhfast(float x) {
    x = fmaxf(x, -15.f);
    float e = __expf(-2.f * x);
    return (1.f - e) / (1.f + e);
}

// B fragments pre-permuted: idx = ((nt*6 + kt)*64 + lane)*8 + i
// n = nt*16 + (lane&15); k = kt*32 + (lane>>4)*8 + i
// W_cat[n][k]: k<64 -> W_ih[n][k], else W_hh[n][k-64]. Split bf16 hi/lo.
// ewp[ke][4] = {Wemb[ke][0], Wemb[ke][1], bemb[ke], 0}
__global__ void prep_kernel(const float* __restrict__ Wih, const float* __restrict__ Whh,
                            const float* __restrict__ Wemb, const float* __restrict__ bemb,
                            unsigned short* __restrict__ BpHi, unsigned short* __restrict__ BpLo,
                            float* __restrict__ ewp) {
    int idx = blockIdx.x * blockDim.x + threadIdx.x;
    if (idx < 64) {
        ewp[idx * 4 + 0] = Wemb[idx * 2 + 0];
        ewp[idx * 4 + 1] = Wemb[idx * 2 + 1];
        ewp[idx * 4 + 2] = bemb[idx];
        ewp[idx * 4 + 3] = 0.f;
    }
    if (idx >= 32 * 6 * 64 * 8) return;
    int i  = idx & 7;
    int l  = (idx >> 3) & 63;
    int v  = idx >> 9;
    int kt = v % 6, nt = v / 6;
    int n = nt * 16 + (l & 15);
    int k = kt * 32 + ((l >> 4) << 3) + i;
    float val = (k < EMB) ? Wih[n * EMB + k] : Whh[n * RNN + (k - EMB)];
    unsigned short hb = f2bf(val);
    BpHi[idx] = hb;
    BpLo[idx] = f2bf(val - bf2f(hb));
}

// LDS (100.8 KB) already limits to 1 block/CU = 8 waves = 2 waves/SIMD.
// Tell the allocator exactly that, so it may use up to 256 VGPRs (not 128)
// and keep the 96-VGPR Bh set resident instead of spilling to scratch.
__global__ __attribute__((amdgpu_flat_work_group_size(NT, NT), amdgpu_waves_per_eu(2, 2)))
void lstm_kernel(
    const float* __restrict__ obs,
    const float* __restrict__ ewp,
    const float* __restrict__ bih,  const float* __restrict__ bhh,
    const unsigned short* __restrict__ BpHi, const unsigned short* __restrict__ BpLo,
    const float* __restrict__ Wout, const float* __restrict__ bout,
    float* __restrict__ out)
{
    // A = [e(64) ; h(128)] bf16 hi/lo planes, row-major [64 ped][192 k], XOR-swizzled,
    // double-buffered across steps.
    __shared__ __align__(16) char smA[2][2][64 * KTOT * 2];  // [buf][hi/lo]
    __shared__ float part[64 * 2 * 4];
    __shared__ float outs[64 * 2];

    const int tid = threadIdx.x;
    const int l   = tid & 63;
    const int w   = __builtin_amdgcn_readfirstlane(tid >> 6);  // wave 0..7
    const int pg  = blockIdx.x * PB + l;

    // zero buf0 (h region must be 0 at step 0)
    for (int r = tid; r < (64 * KTOT * 2) / 4; r += NT) {
        ((int*)smA[0][0])[r] = 0;
        ((int*)smA[0][1])[r] = 0;
    }

    // gate bias: n = g*128 + w*16 + (l&15)
    float bias[4];
#pragma unroll
    for (int g = 0; g < 4; ++g) {
        int n = g * RNN + w * 16 + (l & 15);
        bias[g] = bih[n] + bhh[n];
    }

    const short8* BH = (const short8*)BpHi;
    const short8* BL = (const short8*)BpLo;

    // persist Bh in registers: 24 frags = 96 VGPR; empty asm keeps them opaque
    // so the loads can't be rematerialized into the loop.
    short8 Bh[4][6];
#pragma unroll
    for (int g = 0; g < 4; ++g)
#pragma unroll
        for (int kt = 0; kt < 6; ++kt)
            Bh[g][kt] = BH[((g * 8 + w) * 6 + kt) * 64 + l];
#pragma unroll
    for (int g = 0; g < 4; ++g)
#pragma unroll
        for (int kt = 0; kt < 6; ++kt)
            asm volatile("" : "+v"(Bh[g][kt]));

    // Bl rotation buffer; preload kt=0
    short8 bl[2][4];
#pragma unroll
    for (int g = 0; g < 4; ++g)
        bl[0][g] = BL[((g * 8 + w) * 6 + 0) * 64 + l];

    float c[16];
#pragma unroll
    for (int q = 0; q < 16; ++q) c[q] = 0.f;

    const int jlane = w * 16 + (l & 15);   // this lane's j column
    const int lrow  = (l >> 4) << 2;       // C/D row base
    const int kgrp  = (l >> 4) << 3;       // A/B k-group base

    int cur = 0;
    __syncthreads();  // zero-init visible

    for (int step = 0; step < TSTEPS; ++step) {
        const int nxt = cur ^ 1;

        // ---- E: e = relu(x @ Wemb.T + bemb) -> smA[cur] k=0..63
        float x0, x1;
        if (step < SEQ) {
            const float* xp = obs + ((size_t)step * PEDS + pg) * 2;
            x0 = xp[0]; x1 = xp[1];
        } else {
            x0 = outs[l * 2 + 0];
            x1 = outs[l * 2 + 1];
        }
        {
            short8 vh, vl;
#pragma unroll
            for (int q = 0; q < 8; ++q) {
                const f32x4 ew = *(const f32x4*)(ewp + (w * 8 + q) * 4);
                float v = fmaf(x0, ew[0], fmaf(x1, ew[1], ew[2]));
                v = v > 0.f ? v : 0.f;
                unsigned short hb = f2bf(v);
                vh[q] = (short)hb;
                vl[q] = (short)f2bf(v - bf2f(hb));
            }
            int off = (l * 384 + w * 16) ^ ((l & 7) << 4);
            *(short8*)(smA[cur][0] + off) = vh;
            *(short8*)(smA[cur][1] + off) = vl;
        }
        __syncthreads();  // B1: e (this step) + h (prev step) in smA[cur] visible

        // ---- G: gates[64x512] = A[64x192] @ B[192x512] + bias (bf16x3 MFMA)
        f32x4 acc[4][4];  // [mt][gate]
#pragma unroll
        for (int mt = 0; mt < 4; ++mt)
#pragma unroll
            for (int g = 0; g < 4; ++g) {
                acc[mt][g][0] = bias[g]; acc[mt][g][1] = bias[g];
                acc[mt][g][2] = bias[g]; acc[mt][g][3] = bias[g];
            }
#pragma unroll
        for (int kt = 0; kt < 6; ++kt) {
            const int pcur = kt & 1, pnxt = pcur ^ 1;
            // cyclic prefetch: next kt's Bl (kt=5 prefetches kt=0 for next step)
            const int ktn = (kt < 5) ? kt + 1 : 0;
#pragma unroll
            for (int g = 0; g < 4; ++g)
                bl[pnxt][g] = BL[((g * 8 + w) * 6 + ktn) * 64 + l];
#pragma unroll
            for (int mt = 0; mt < 4; ++mt) {
                int ped = mt * 16 + (l & 15);
                int off = (ped * 384 + (kt * 32 + kgrp) * 2) ^ ((ped & 7) << 4);
                short8 ah = *(const short8*)(smA[cur][0] + off);
                short8 al = *(const short8*)(smA[cur][1] + off);
#pragma unroll
                for (int g = 0; g < 4; ++g) {
                    acc[mt][g] = __builtin_amdgcn_mfma_f32_16x16x32_bf16(ah, Bh[g][kt], acc[mt][g], 0, 0, 0);
                    acc[mt][g] = __builtin_amdgcn_mfma_f32_16x16x32_bf16(al, Bh[g][kt], acc[mt][g], 0, 0, 0);
                    acc[mt][g] = __builtin_amdgcn_mfma_f32_16x16x32_bf16(ah, bl[pcur][g], acc[mt][g], 0, 0, 0);
                }
            }
        }

        // ---- S: nonlinearities + c/h update; h_new -> smA[nxt] (ordered by B1)
#pragma unroll
        for (int mt = 0; mt < 4; ++mt) {
#pragma unroll
            for (int r = 0; r < 4; ++r) {
                float gi = acc[mt][0][r], gf = acc[mt][1][r];
                float gg = acc[mt][2][r], go = acc[mt][3][r];
                float i_ = sigm(gi), f_ = sigm(gf), g_ = tanhfast(gg), o_ = sigm(go);
                float cn = fmaf(f_, c[mt * 4 + r], i_ * g_);
                c[mt * 4 + r] = cn;
                float hn = o_ * tanhfast(cn);
                int ped = mt * 16 + lrow + r;
                unsigned short hb = f2bf(hn);
                unsigned short lb = f2bf(hn - bf2f(hb));
                int offb = (ped * 384 + (EMB + jlane) * 2) ^ ((ped & 7) << 4);
                *(short*)(smA[nxt][0] + offb) = (short)hb;
                *(short*)(smA[nxt][1] + offb) = (short)lb;
            }
        }

        // ---- O: out = h @ Wout.T + bout, h reconstructed as hi+lo from smA[nxt]
        if (step >= SEQ - 1) {
            __syncthreads();  // B3: h(step) in smA[nxt] visible
            const int oo = w & 1, jq = w >> 1;
            float s = 0.f;
#pragma unroll
            for (int t = 0; t < 4; ++t) {
                int j = jq * 32 + t * 8;
                int off = (l * 384 + (EMB + j) * 2) ^ ((l & 7) << 4);
                short8 hh = *(const short8*)(smA[nxt][0] + off);
                short8 hl = *(const short8*)(smA[nxt][1] + off);
                const f32x4 w0 = *(const f32x4*)(Wout + oo * RNN + j);
                const f32x4 w1 = *(const f32x4*)(Wout + oo * RNN + j + 4);
#pragma unroll
                for (int i = 0; i < 4; ++i) {
                    s = fmaf(bf2f((unsigned short)hh[i]) + bf2f((unsigned short)hl[i]), w0[i], s);
                    s = fmaf(bf2f((unsigned short)hh[i + 4]) + bf2f((unsigned short)hl[i + 4]), w1[i], s);
                }
            }
            part[(l * 2 + oo) * 4 + jq] = s;
            __syncthreads();  // B4
            if (tid < 128) {
                int pp = tid & 63, o2 = tid >> 6;
                const float* pr = &part[(pp * 2 + o2) * 4];
                float o = bout[o2] + ((pr[0] + pr[1]) + (pr[2] + pr[3]));
                outs[pp * 2 + o2] = o;
                if (step >= SEQ)
                    out[((size_t)(step - SEQ) * PEDS + (blockIdx.x * PB + pp)) * 2 + o2] = o;
            }
            __syncthreads();  // B5: outs visible for next E
        }
        cur = nxt;
    }
}

extern "C" void kernel_launch(void* const* d_in, const int* in_sizes, int n_in,
                              void* d_out, int out_size, void* d_ws, size_t ws_size,
                              hipStream_t stream) {
    const float* obs  = (const float*)d_in[0];
    const float* Wemb = (const float*)d_in[1];
    const float* bemb = (const float*)d_in[2];
    const float* Wih  = (const float*)d_in[3];
    const float* bih  = (const float*)d_in[4];
    const float* Whh  = (const float*)d_in[5];
    const float* bhh  = (const float*)d_in[6];
    const float* Wout = (const float*)d_in[7];
    const float* bout = (const float*)d_in[8];

    unsigned short* BpHi = (unsigned short*)d_ws;       // 98304 u16 = 192 KB
    unsigned short* BpLo = BpHi + 32 * 6 * 64 * 8;      // 192 KB
    float*          ewp  = (float*)(BpLo + 32 * 6 * 64 * 8);  // 64*4 f32 = 1 KB

    prep_kernel<<<(32 * 6 * 64 * 8 + 255) / 256, 256, 0, stream>>>(Wih, Whh, Wemb, bemb, BpHi, BpLo, ewp);
    lstm_kernel<<<PEDS / PB, NT, 0, stream>>>(obs, ewp, bih, bhh,
                                              BpHi, BpLo, Wout, bout, (float*)d_out);
}